// Round 1
// baseline (653.655 us; speedup 1.0000x reference)
//
#include <hip/hip_runtime.h>
#include <hip/hip_bf16.h>

// Problem constants (B,T,C,H) = (8, 2048, 1024, 128)
constexpr int Bz = 8, Tt = 2048, Cc = 1024, Hh = 128;
constexpr int Mrows = Bz * Tt;                 // 16384
constexpr float kScale = 0.08838834764831843f; // 1/sqrt(128)

// ---------------------------------------------------------------------------
// Kernel 1: fused QKV projection.  out[m,n] = sum_k x[m,k] * W[k,n]
// M=16384, K=1024, N=128.  BM=64, BN=128(full), BK=32. block=256.
// blockIdx.z selects which of Wq/Wk/Wv (and output buffer).
// ---------------------------------------------------------------------------
__global__ __launch_bounds__(256) void qkv_kernel(
    const float* __restrict__ x,
    const float* __restrict__ Wq, const float* __restrict__ Wk,
    const float* __restrict__ Wv,
    float* __restrict__ qo, float* __restrict__ ko, float* __restrict__ vo)
{
    __shared__ float xs[64][32];   // 8 KB
    __shared__ float ws[32][128];  // 16 KB

    const int tid = threadIdx.x;
    const int m0  = blockIdx.x * 64;

    const float* W; float* outp;
    if      (blockIdx.z == 0) { W = Wq; outp = qo; }
    else if (blockIdx.z == 1) { W = Wk; outp = ko; }
    else                      { W = Wv; outp = vo; }

    const int tn = tid & 31;   // cols 4*tn .. 4*tn+3
    const int tm = tid >> 5;   // rows 8*tm .. 8*tm+7

    float acc[8][4];
#pragma unroll
    for (int i = 0; i < 8; ++i)
#pragma unroll
        for (int j = 0; j < 4; ++j) acc[i][j] = 0.f;

    for (int k0 = 0; k0 < Cc; k0 += 32) {
        // stage x tile 64x32 (512 float4, 2 per thread)
#pragma unroll
        for (int u = 0; u < 2; ++u) {
            int f = tid + u * 256;
            int r = f >> 3, c = f & 7;
            *reinterpret_cast<float4*>(&xs[r][c * 4]) =
                *reinterpret_cast<const float4*>(&x[(size_t)(m0 + r) * Cc + k0 + c * 4]);
        }
        // stage W tile 32x128 (1024 float4, 4 per thread)
#pragma unroll
        for (int u = 0; u < 4; ++u) {
            int f = tid + u * 256;
            int r = f >> 5, c = f & 31;
            *reinterpret_cast<float4*>(&ws[r][c * 4]) =
                *reinterpret_cast<const float4*>(&W[(size_t)(k0 + r) * Hh + c * 4]);
        }
        __syncthreads();
#pragma unroll
        for (int kk = 0; kk < 32; ++kk) {
            float4 wv = *reinterpret_cast<const float4*>(&ws[kk][tn * 4]);
#pragma unroll
            for (int i = 0; i < 8; ++i) {
                float xv = xs[tm * 8 + i][kk];  // broadcast read (2 addrs/wave)
                acc[i][0] += xv * wv.x;
                acc[i][1] += xv * wv.y;
                acc[i][2] += xv * wv.z;
                acc[i][3] += xv * wv.w;
            }
        }
        __syncthreads();
    }
#pragma unroll
    for (int i = 0; i < 8; ++i) {
        float4 t4 = make_float4(acc[i][0], acc[i][1], acc[i][2], acc[i][3]);
        *reinterpret_cast<float4*>(&outp[(size_t)(m0 + tm * 8 + i) * Hh + tn * 4]) = t4;
    }
}

// ---------------------------------------------------------------------------
// Kernel 2: causal flash attention (fp32).  BQ=32, BKV=32, block=256.
// grid = (T/32, B).  Writes pre-projection O into d_out (projected in-place
// by kernel 3 afterwards).
// ---------------------------------------------------------------------------
__global__ __launch_bounds__(256) void attn_kernel(
    const float* __restrict__ qw, const float* __restrict__ kw,
    const float* __restrict__ vw, float* __restrict__ O)
{
    __shared__ float qs[32][132];  // padded: stride 132 floats
    __shared__ float ks[32][132];
    __shared__ float vs[32][132];
    __shared__ float ss[32][33];   // S / P tile
    __shared__ float m_s[32], l_s[32], f_s[32];

    const int tid  = threadIdx.x;
    const int b    = blockIdx.y;
    // reverse so heavy (late) q-blocks dispatch first
    const int qblk = (int)gridDim.x - 1 - (int)blockIdx.x;
    const int q0   = qblk * 32;

    const float* qbase = qw + (size_t)(b * Tt) * Hh;
    const float* kbase = kw + (size_t)(b * Tt) * Hh;
    const float* vbase = vw + (size_t)(b * Tt) * Hh;

    // stage Q tile once
#pragma unroll
    for (int u = 0; u < 4; ++u) {
        int f = tid + u * 256;
        int r = f >> 5, c = f & 31;
        *reinterpret_cast<float4*>(&qs[r][c * 4]) =
            *reinterpret_cast<const float4*>(&qbase[(size_t)(q0 + r) * Hh + c * 4]);
    }
    if (tid < 32) { m_s[tid] = -1e30f; l_s[tid] = 0.f; }

    // S-phase ownership: 2x2 micro-tile
    const int c2 = tid & 15;   // cols 2*c2, 2*c2+1
    const int r2 = tid >> 4;   // rows 2*r2, 2*r2+1
    // softmax ownership: 8 lanes per row
    const int srow = tid >> 3;
    const int l8   = tid & 7;
    // PV / O ownership: rows {2g,2g+1}, 8 h each
    const int g  = tid >> 4;
    const int h0 = (tid & 15) * 8;

    float o[2][8];
#pragma unroll
    for (int r = 0; r < 2; ++r)
#pragma unroll
        for (int u = 0; u < 8; ++u) o[r][u] = 0.f;

    __syncthreads();

    for (int gg = 0; gg <= qblk; ++gg) {
        const int kv0 = gg * 32;
        // stage K,V tiles
#pragma unroll
        for (int u = 0; u < 4; ++u) {
            int f = tid + u * 256;
            int r = f >> 5, c = f & 31;
            *reinterpret_cast<float4*>(&ks[r][c * 4]) =
                *reinterpret_cast<const float4*>(&kbase[(size_t)(kv0 + r) * Hh + c * 4]);
            *reinterpret_cast<float4*>(&vs[r][c * 4]) =
                *reinterpret_cast<const float4*>(&vbase[(size_t)(kv0 + r) * Hh + c * 4]);
        }
        __syncthreads();

        // S = scale * Q K^T  (2x2 per thread), causal mask
        float s00 = 0.f, s01 = 0.f, s10 = 0.f, s11 = 0.f;
#pragma unroll
        for (int h4 = 0; h4 < 32; ++h4) {
            float4 qa = *reinterpret_cast<const float4*>(&qs[2 * r2][h4 * 4]);
            float4 qb = *reinterpret_cast<const float4*>(&qs[2 * r2 + 1][h4 * 4]);
            float4 ka = *reinterpret_cast<const float4*>(&ks[2 * c2][h4 * 4]);
            float4 kb = *reinterpret_cast<const float4*>(&ks[2 * c2 + 1][h4 * 4]);
            s00 += qa.x * ka.x + qa.y * ka.y + qa.z * ka.z + qa.w * ka.w;
            s01 += qa.x * kb.x + qa.y * kb.y + qa.z * kb.z + qa.w * kb.w;
            s10 += qb.x * ka.x + qb.y * ka.y + qb.z * ka.z + qb.w * ka.w;
            s11 += qb.x * kb.x + qb.y * kb.y + qb.z * kb.z + qb.w * kb.w;
        }
        {
            const int qi0 = q0 + 2 * r2, qi1 = qi0 + 1;
            const int kj0 = kv0 + 2 * c2, kj1 = kj0 + 1;
            ss[2 * r2][2 * c2]         = (kj0 <= qi0) ? s00 * kScale : -1e30f;
            ss[2 * r2][2 * c2 + 1]     = (kj1 <= qi0) ? s01 * kScale : -1e30f;
            ss[2 * r2 + 1][2 * c2]     = (kj0 <= qi1) ? s10 * kScale : -1e30f;
            ss[2 * r2 + 1][2 * c2 + 1] = (kj1 <= qi1) ? s11 * kScale : -1e30f;
        }
        __syncthreads();

        // online softmax over this 32-wide slab
        {
            float v0 = ss[srow][l8 * 4 + 0];
            float v1 = ss[srow][l8 * 4 + 1];
            float v2 = ss[srow][l8 * 4 + 2];
            float v3 = ss[srow][l8 * 4 + 3];
            float mx = fmaxf(fmaxf(v0, v1), fmaxf(v2, v3));
            mx = fmaxf(mx, __shfl_xor(mx, 1));
            mx = fmaxf(mx, __shfl_xor(mx, 2));
            mx = fmaxf(mx, __shfl_xor(mx, 4));
            float m_old = m_s[srow];
            float m_new = fmaxf(m_old, mx);
            float p0 = __expf(v0 - m_new);
            float p1 = __expf(v1 - m_new);
            float p2 = __expf(v2 - m_new);
            float p3 = __expf(v3 - m_new);
            float rs = p0 + p1 + p2 + p3;
            rs += __shfl_xor(rs, 1);
            rs += __shfl_xor(rs, 2);
            rs += __shfl_xor(rs, 4);
            ss[srow][l8 * 4 + 0] = p0;
            ss[srow][l8 * 4 + 1] = p1;
            ss[srow][l8 * 4 + 2] = p2;
            ss[srow][l8 * 4 + 3] = p3;
            if (l8 == 0) {
                float fct = __expf(m_old - m_new);
                m_s[srow] = m_new;
                l_s[srow] = l_s[srow] * fct + rs;
                f_s[srow] = fct;
            }
        }
        __syncthreads();

        // O = O*f + P @ V
        {
            float f0 = f_s[2 * g], f1 = f_s[2 * g + 1];
#pragma unroll
            for (int u = 0; u < 8; ++u) { o[0][u] *= f0; o[1][u] *= f1; }
#pragma unroll 8
            for (int j = 0; j < 32; ++j) {
                float p0 = ss[2 * g][j], p1 = ss[2 * g + 1][j];
                float4 va = *reinterpret_cast<const float4*>(&vs[j][h0]);
                float4 vb = *reinterpret_cast<const float4*>(&vs[j][h0 + 4]);
                o[0][0] += p0 * va.x; o[0][1] += p0 * va.y;
                o[0][2] += p0 * va.z; o[0][3] += p0 * va.w;
                o[0][4] += p0 * vb.x; o[0][5] += p0 * vb.y;
                o[0][6] += p0 * vb.z; o[0][7] += p0 * vb.w;
                o[1][0] += p1 * va.x; o[1][1] += p1 * va.y;
                o[1][2] += p1 * va.z; o[1][3] += p1 * va.w;
                o[1][4] += p1 * vb.x; o[1][5] += p1 * vb.y;
                o[1][6] += p1 * vb.z; o[1][7] += p1 * vb.w;
            }
        }
        __syncthreads();
    }

    // finalize: divide by running denom, write pre-projection O
    {
        float inv0 = 1.f / l_s[2 * g];
        float inv1 = 1.f / l_s[2 * g + 1];
        const size_t row0 = (size_t)(b * Tt + q0 + 2 * g) * Hh;
        const size_t row1 = (size_t)(b * Tt + q0 + 2 * g + 1) * Hh;
        float4 a0 = make_float4(o[0][0] * inv0, o[0][1] * inv0, o[0][2] * inv0, o[0][3] * inv0);
        float4 a1 = make_float4(o[0][4] * inv0, o[0][5] * inv0, o[0][6] * inv0, o[0][7] * inv0);
        float4 b0 = make_float4(o[1][0] * inv1, o[1][1] * inv1, o[1][2] * inv1, o[1][3] * inv1);
        float4 b1 = make_float4(o[1][4] * inv1, o[1][5] * inv1, o[1][6] * inv1, o[1][7] * inv1);
        *reinterpret_cast<float4*>(&O[row0 + h0])     = a0;
        *reinterpret_cast<float4*>(&O[row0 + h0 + 4]) = a1;
        *reinterpret_cast<float4*>(&O[row1 + h0])     = b0;
        *reinterpret_cast<float4*>(&O[row1 + h0 + 4]) = b1;
    }
}

// ---------------------------------------------------------------------------
// Kernel 3: in-place output projection.  out[m,h] = O[m,:] @ Wp[:,h] + bp[h]
// BM=64 rows per block; O tile staged in LDS before overwrite (in-place safe).
// ---------------------------------------------------------------------------
__global__ __launch_bounds__(256) void proj_kernel(
    float* __restrict__ io, const float* __restrict__ Wp,
    const float* __restrict__ bp)
{
    __shared__ float os[64][128];  // 32 KB
    const int tid = threadIdx.x;
    const int m0  = blockIdx.x * 64;

#pragma unroll
    for (int u = 0; u < 8; ++u) {
        int f = tid + u * 256;
        int r = f >> 5, c = f & 31;
        *reinterpret_cast<float4*>(&os[r][c * 4]) =
            *reinterpret_cast<const float4*>(&io[(size_t)(m0 + r) * Hh + c * 4]);
    }
    __syncthreads();

    const int h  = tid & 127;
    const int rr = tid >> 7;  // 0..1 -> rows rr*32 .. rr*32+31
    float acc[32];
#pragma unroll
    for (int i = 0; i < 32; ++i) acc[i] = 0.f;

    for (int k = 0; k < 128; ++k) {
        float w = Wp[k * Hh + h];   // coalesced across lanes
#pragma unroll
        for (int i = 0; i < 32; ++i) acc[i] += os[rr * 32 + i][k] * w;  // broadcast
    }
    float bv = bp[h];
#pragma unroll
    for (int i = 0; i < 32; ++i)
        io[(size_t)(m0 + rr * 32 + i) * Hh + h] = acc[i] + bv;
}

// ---------------------------------------------------------------------------
extern "C" void kernel_launch(void* const* d_in, const int* in_sizes, int n_in,
                              void* d_out, int out_size, void* d_ws, size_t ws_size,
                              hipStream_t stream) {
    const float* x  = (const float*)d_in[0];
    const float* Wk = (const float*)d_in[1];
    const float* Wq = (const float*)d_in[2];
    const float* Wv = (const float*)d_in[3];
    const float* Wp = (const float*)d_in[4];
    const float* bp = (const float*)d_in[5];
    float* out = (float*)d_out;

    // workspace: q,k,v fp32 [16384,128] each = 25.2 MB total
    float* qw = (float*)d_ws;
    float* kw = qw + (size_t)Mrows * Hh;
    float* vw = kw + (size_t)Mrows * Hh;

    qkv_kernel<<<dim3(Mrows / 64, 1, 3), 256, 0, stream>>>(x, Wq, Wk, Wv, qw, kw, vw);
    attn_kernel<<<dim3(Tt / 32, Bz), 256, 0, stream>>>(qw, kw, vw, out);
    proj_kernel<<<dim3(Mrows / 64), 256, 0, stream>>>(out, Wp, bp);
}

// Round 2
// 207.523 us; speedup vs baseline: 3.1498x; 3.1498x over previous
//
#include <hip/hip_runtime.h>

// Problem constants (B,T,C,H) = (8, 2048, 1024, 128)
constexpr int Bz = 8, Tt = 2048, Cc = 1024, Hh = 128;
constexpr int Mrows = Bz * Tt;                 // 16384
constexpr float kScale = 0.08838834764831843f; // 1/sqrt(128)

typedef float f32x4 __attribute__((ext_vector_type(4)));
typedef short s16x8 __attribute__((ext_vector_type(8)));
typedef short s16x4 __attribute__((ext_vector_type(4)));
typedef unsigned short u16;

static __device__ __forceinline__ u16 f2bf(float f) {
    union { float f; unsigned int u; } c; c.f = f;
    unsigned int u = c.u;
    unsigned int r = (u + 0x7fffu + ((u >> 16) & 1u)) >> 16;   // RNE
    return (u16)r;
}

// ---------------------------------------------------------------------------
// Kernel 0: transpose+convert weights.  wt[z][n][k] = bf16(W_z[k][n])
// z: 0=Wq, 1=Wk, 2=Wv.  3*128*1024 elements.
// ---------------------------------------------------------------------------
__global__ __launch_bounds__(256) void convw_kernel(
    const float* __restrict__ Wq, const float* __restrict__ Wk,
    const float* __restrict__ Wv, u16* __restrict__ wt)
{
    int i = blockIdx.x * 256 + threadIdx.x;      // < 393216
    int z = i >> 17, r = i & 131071;
    int n = r >> 10, k = r & 1023;
    const float* W = (z == 0) ? Wq : (z == 1) ? Wk : Wv;
    wt[i] = f2bf(W[k * Hh + n]);
}

// ---------------------------------------------------------------------------
// Kernel 1: QKV GEMM, bf16 MFMA 16x16x32.  BM=128, BN=128(full H), BK=32.
// A = x (fp32->bf16 during staging), B = wt[z] ([n][k] bf16, pre-transposed).
// 4 waves, wave tile 64x64.  LDS XOR-swizzled (4-way max on frag reads).
// ---------------------------------------------------------------------------
__global__ __launch_bounds__(256) void qkv_gemm(
    const float* __restrict__ x, const u16* __restrict__ wt,
    u16* __restrict__ qo, u16* __restrict__ ko, u16* __restrict__ vo)
{
    __shared__ __align__(16) u16 as[128 * 32];
    __shared__ __align__(16) u16 bs[128 * 32];

    const int tid  = threadIdx.x;
    const int m0   = blockIdx.x * 128;
    const int lane = tid & 63, wid = tid >> 6;
    const int wr   = wid >> 1, wc = wid & 1;
    const int l15  = lane & 15, l4 = lane >> 4;

    const u16* W = wt + (size_t)blockIdx.z * 128 * 1024;
    u16* outp = (blockIdx.z == 0) ? qo : (blockIdx.z == 1) ? ko : vo;

    f32x4 acc[4][4];
#pragma unroll
    for (int mi = 0; mi < 4; ++mi)
#pragma unroll
        for (int ni = 0; ni < 4; ++ni) {
            f32x4 z4 = {0.f, 0.f, 0.f, 0.f};
            acc[mi][ni] = z4;
        }

    for (int k0 = 0; k0 < Cc; k0 += 32) {
        // stage A: 128x32 fp32 -> bf16, swizzled (ushort idx: m*32 + (k ^ ((m&3)<<3)))
#pragma unroll
        for (int u = 0; u < 4; ++u) {
            int c = tid + u * 256;               // 0..1023
            int m = c >> 3, kf = (c & 7) * 4;    // 4 floats
            float4 xv = *reinterpret_cast<const float4*>(
                &x[(size_t)(m0 + m) * Cc + k0 + kf]);
            s16x4 bv;
            bv[0] = (short)f2bf(xv.x); bv[1] = (short)f2bf(xv.y);
            bv[2] = (short)f2bf(xv.z); bv[3] = (short)f2bf(xv.w);
            *reinterpret_cast<s16x4*>(&as[m * 32 + (kf ^ ((m & 3) << 3))]) = bv;
        }
        // stage B: 128x32 bf16 rows from wt ([n][k]), swizzled
#pragma unroll
        for (int u = 0; u < 2; ++u) {
            int c = tid + u * 256;               // 0..511
            int n = c >> 2, ks = (c & 3) * 8;    // 8 ushorts
            s16x8 wv = *reinterpret_cast<const s16x8*>(&W[(size_t)n * 1024 + k0 + ks]);
            *reinterpret_cast<s16x8*>(&bs[n * 32 + (ks ^ ((n & 3) << 3))]) = wv;
        }
        __syncthreads();

        s16x8 af[4], bf[4];
#pragma unroll
        for (int mi = 0; mi < 4; ++mi) {
            int r = wr * 64 + mi * 16 + l15;
            af[mi] = *reinterpret_cast<const s16x8*>(
                &as[r * 32 + ((l4 * 8) ^ ((r & 3) << 3))]);
        }
#pragma unroll
        for (int ni = 0; ni < 4; ++ni) {
            int n = wc * 64 + ni * 16 + l15;
            bf[ni] = *reinterpret_cast<const s16x8*>(
                &bs[n * 32 + ((l4 * 8) ^ ((n & 3) << 3))]);
        }
#pragma unroll
        for (int mi = 0; mi < 4; ++mi)
#pragma unroll
            for (int ni = 0; ni < 4; ++ni)
                acc[mi][ni] = __builtin_amdgcn_mfma_f32_16x16x32_bf16(
                    af[mi], bf[ni], acc[mi][ni], 0, 0, 0);
        __syncthreads();
    }

    // epilogue: D row=(l>>4)*4+reg, col=l&15 per 16x16 frag
#pragma unroll
    for (int mi = 0; mi < 4; ++mi)
#pragma unroll
        for (int ni = 0; ni < 4; ++ni)
#pragma unroll
            for (int r = 0; r < 4; ++r) {
                int row = m0 + wr * 64 + mi * 16 + l4 * 4 + r;
                int col = wc * 64 + ni * 16 + l15;
                outp[(size_t)row * Hh + col] = f2bf(acc[mi][ni][r]);
            }
}

// ---------------------------------------------------------------------------
// Kernel 2: transpose V.  vt[b][h][t] = v[b][t][h]  (bf16)
// Reads coalesced (lane = h); writes 16B/thread, 64B/thread contiguous per row.
// ---------------------------------------------------------------------------
__global__ __launch_bounds__(256) void vtrans_kernel(
    const u16* __restrict__ v, u16* __restrict__ vt)
{
    const int b = blockIdx.y;
    const int t0 = blockIdx.x * 64;
    const int h = threadIdx.x & 127;
    const int part = threadIdx.x >> 7;
    const u16* vb = v + (size_t)b * Tt * Hh;
    u16* vtb = vt + (size_t)b * Hh * Tt;
#pragma unroll
    for (int u = 0; u < 4; ++u) {
        int tt = t0 + (part * 4 + u) * 8;
        union { u16 u[8]; s16x8 v; } tmp;
#pragma unroll
        for (int j = 0; j < 8; ++j) tmp.u[j] = vb[(size_t)(tt + j) * Hh + h];
        *reinterpret_cast<s16x8*>(&vtb[(size_t)h * Tt + tt]) = tmp.v;
    }
}

// ---------------------------------------------------------------------------
// Kernel 3: causal flash attention, bf16 MFMA.  BQ=64 (4 waves x 16 rows),
// BKV=64.  K LDS [64][128] swizzled; Vt LDS [128][64] swizzled; P via
// per-wave swizzled LDS.  Writes fp32 O to d_out.
// ---------------------------------------------------------------------------
__global__ __launch_bounds__(256) void attn_kernel(
    const u16* __restrict__ q, const u16* __restrict__ k,
    const u16* __restrict__ vt, float* __restrict__ O)
{
    __shared__ __align__(16) u16 ksl[64 * 128];   // 16 KB
    __shared__ __align__(16) u16 vsl[128 * 64];   // 16 KB
    __shared__ __align__(16) u16 psl[4 * 16 * 64];// 8 KB

    const int tid = threadIdx.x, lane = tid & 63, wid = tid >> 6;
    const int b = blockIdx.y;
    const int qblk = 31 - (int)blockIdx.x;        // heavy blocks first
    const int q0 = qblk * 64;
    const int l15 = lane & 15, l4 = lane >> 4;

    const u16* qb = q + (size_t)b * Tt * Hh;
    const u16* kb = k + (size_t)b * Tt * Hh;
    const u16* vb = vt + (size_t)b * Hh * Tt;

    // Q fragments in registers (A-operand): row = q0+wid*16+l15, k = ks*32+l4*8
    s16x8 qf[4];
#pragma unroll
    for (int ks = 0; ks < 4; ++ks)
        qf[ks] = *reinterpret_cast<const s16x8*>(
            &qb[(size_t)(q0 + wid * 16 + l15) * Hh + ks * 32 + l4 * 8]);

    f32x4 o[8];
#pragma unroll
    for (int nh = 0; nh < 8; ++nh) { f32x4 z4 = {0.f,0.f,0.f,0.f}; o[nh] = z4; }
    float mreg[4], lreg[4];
#pragma unroll
    for (int r = 0; r < 4; ++r) { mreg[r] = -1e30f; lreg[r] = 0.f; }

    u16* ps = &psl[wid * 16 * 64];
    const int nt = qblk + 1;

    for (int j = 0; j < nt; ++j) {
        const int kv0 = j * 64;
        // stage K tile: 64 rows x 128 ushorts, swizzle ((r&7)<<3 ushorts)
#pragma unroll
        for (int u = 0; u < 4; ++u) {
            int c = tid + u * 256;
            int r = c >> 4, s = (c & 15) * 8;
            s16x8 kv = *reinterpret_cast<const s16x8*>(
                &kb[(size_t)(kv0 + r) * Hh + s]);
            *reinterpret_cast<s16x8*>(&ksl[r * 128 + (s ^ ((r & 7) << 3))]) = kv;
        }
        // stage Vt tile: 128 rows x 64 ushorts, swizzle ((h&7)<<3)
#pragma unroll
        for (int u = 0; u < 4; ++u) {
            int c = tid + u * 256;
            int hr = c >> 3, s = (c & 7) * 8;
            s16x8 vv = *reinterpret_cast<const s16x8*>(
                &vb[(size_t)hr * Tt + kv0 + s]);
            *reinterpret_cast<s16x8*>(&vsl[hr * 64 + (s ^ ((hr & 7) << 3))]) = vv;
        }
        __syncthreads();

        // S = Q K^T : 16 MFMAs
        f32x4 sacc[4];
#pragma unroll
        for (int nf = 0; nf < 4; ++nf) { f32x4 z4 = {0.f,0.f,0.f,0.f}; sacc[nf] = z4; }
#pragma unroll
        for (int ks = 0; ks < 4; ++ks)
#pragma unroll
            for (int nf = 0; nf < 4; ++nf) {
                int kr = nf * 16 + l15;
                s16x8 kf = *reinterpret_cast<const s16x8*>(
                    &ksl[kr * 128 + ((ks * 32 + l4 * 8) ^ ((kr & 7) << 3))]);
                sacc[nf] = __builtin_amdgcn_mfma_f32_16x16x32_bf16(
                    qf[ks], kf, sacc[nf], 0, 0, 0);
            }

        // scale + causal mask (diagonal tile only) + online softmax
        const bool diag = (j == nt - 1);
        float pv[4][4];
#pragma unroll
        for (int nf = 0; nf < 4; ++nf)
#pragma unroll
            for (int r = 0; r < 4; ++r) {
                float s = sacc[nf][r] * kScale;
                if (diag) {
                    int qq = wid * 16 + l4 * 4 + r;   // local (q0 == kv0)
                    int kk = nf * 16 + l15;
                    if (kk > qq) s = -1e30f;
                }
                pv[nf][r] = s;
            }
#pragma unroll
        for (int r = 0; r < 4; ++r) {
            float mx = fmaxf(fmaxf(pv[0][r], pv[1][r]), fmaxf(pv[2][r], pv[3][r]));
            mx = fmaxf(mx, __shfl_xor(mx, 1));
            mx = fmaxf(mx, __shfl_xor(mx, 2));
            mx = fmaxf(mx, __shfl_xor(mx, 4));
            mx = fmaxf(mx, __shfl_xor(mx, 8));
            float mnew = fmaxf(mreg[r], mx);
            float scl = __expf(mreg[r] - mnew);
            mreg[r] = mnew;
            float rs = 0.f;
#pragma unroll
            for (int nf = 0; nf < 4; ++nf) {
                float p = __expf(pv[nf][r] - mnew);
                pv[nf][r] = p; rs += p;
            }
            rs += __shfl_xor(rs, 1); rs += __shfl_xor(rs, 2);
            rs += __shfl_xor(rs, 4); rs += __shfl_xor(rs, 8);
            lreg[r] = lreg[r] * scl + rs;
#pragma unroll
            for (int nh = 0; nh < 8; ++nh) o[nh][r] *= scl;
        }

        // P -> per-wave LDS (bf16, swizzled); read back as A-fragments
#pragma unroll
        for (int nf = 0; nf < 4; ++nf)
#pragma unroll
            for (int r = 0; r < 4; ++r) {
                int row = l4 * 4 + r, col = nf * 16 + l15;
                ps[row * 64 + (col ^ ((row & 7) << 3))] = f2bf(pv[nf][r]);
            }

        // O += P V : 16 MFMAs
#pragma unroll
        for (int ks2 = 0; ks2 < 2; ++ks2) {
            s16x8 pa = *reinterpret_cast<const s16x8*>(
                &ps[l15 * 64 + ((ks2 * 32 + l4 * 8) ^ ((l15 & 7) << 3))]);
#pragma unroll
            for (int nh = 0; nh < 8; ++nh) {
                int hr = nh * 16 + l15;
                s16x8 vf = *reinterpret_cast<const s16x8*>(
                    &vsl[hr * 64 + ((ks2 * 32 + l4 * 8) ^ ((hr & 7) << 3))]);
                o[nh] = __builtin_amdgcn_mfma_f32_16x16x32_bf16(pa, vf, o[nh], 0, 0, 0);
            }
        }
        __syncthreads();
    }

    // epilogue: normalize, write fp32 O
    float inv[4];
#pragma unroll
    for (int r = 0; r < 4; ++r) inv[r] = 1.f / lreg[r];
#pragma unroll
    for (int nh = 0; nh < 8; ++nh)
#pragma unroll
        for (int r = 0; r < 4; ++r) {
            int row = q0 + wid * 16 + l4 * 4 + r;
            int col = nh * 16 + l15;
            O[((size_t)(b * Tt) + row) * Hh + col] = o[nh][r] * inv[r];
        }
}

// ---------------------------------------------------------------------------
// Kernel 4: in-place output projection (fp32, unchanged from round 1).
// ---------------------------------------------------------------------------
__global__ __launch_bounds__(256) void proj_kernel(
    float* __restrict__ io, const float* __restrict__ Wp,
    const float* __restrict__ bp)
{
    __shared__ float os[64][128];
    const int tid = threadIdx.x;
    const int m0  = blockIdx.x * 64;
#pragma unroll
    for (int u = 0; u < 8; ++u) {
        int f = tid + u * 256;
        int r = f >> 5, c = f & 31;
        *reinterpret_cast<float4*>(&os[r][c * 4]) =
            *reinterpret_cast<const float4*>(&io[(size_t)(m0 + r) * Hh + c * 4]);
    }
    __syncthreads();

    const int h  = tid & 127;
    const int rr = tid >> 7;
    float acc[32];
#pragma unroll
    for (int i = 0; i < 32; ++i) acc[i] = 0.f;
    for (int k = 0; k < 128; ++k) {
        float w = Wp[k * Hh + h];
#pragma unroll
        for (int i = 0; i < 32; ++i) acc[i] += os[rr * 32 + i][k] * w;
    }
    float bv = bp[h];
#pragma unroll
    for (int i = 0; i < 32; ++i)
        io[(size_t)(m0 + rr * 32 + i) * Hh + h] = acc[i] + bv;
}

// ---------------------------------------------------------------------------
extern "C" void kernel_launch(void* const* d_in, const int* in_sizes, int n_in,
                              void* d_out, int out_size, void* d_ws, size_t ws_size,
                              hipStream_t stream) {
    const float* x  = (const float*)d_in[0];
    const float* Wk = (const float*)d_in[1];
    const float* Wq = (const float*)d_in[2];
    const float* Wv = (const float*)d_in[3];
    const float* Wp = (const float*)d_in[4];
    const float* bp = (const float*)d_in[5];
    float* out = (float*)d_out;

    // workspace layout (ushorts): wt 393216 | qw 2M | kw 2M | vw 2M | vt 2M
    u16* wtb = (u16*)d_ws;
    u16* qw = wtb + 393216;
    u16* kw = qw + (size_t)Mrows * Hh;
    u16* vw = kw + (size_t)Mrows * Hh;
    u16* vtb = vw + (size_t)Mrows * Hh;   // total ~17.6 MB

    convw_kernel<<<1536, 256, 0, stream>>>(Wq, Wk, Wv, wtb);
    qkv_gemm<<<dim3(Mrows / 128, 1, 3), 256, 0, stream>>>(x, wtb, qw, kw, vw);
    vtrans_kernel<<<dim3(Tt / 64, Bz), 256, 0, stream>>>(vw, vtb);
    attn_kernel<<<dim3(Tt / 64, Bz), 256, 0, stream>>>(qw, kw, vtb, out);
    proj_kernel<<<dim3(Mrows / 64), 256, 0, stream>>>(out, Wp, bp);
}

// Round 3
// 158.480 us; speedup vs baseline: 4.1245x; 1.3095x over previous
//
#include <hip/hip_runtime.h>

// Problem constants (B,T,C,H) = (8, 2048, 1024, 128)
constexpr int Bz = 8, Tt = 2048, Cc = 1024, Hh = 128;
constexpr int Mrows = Bz * Tt;                 // 16384
constexpr float kScale = 0.08838834764831843f; // 1/sqrt(128)

typedef float f32x4 __attribute__((ext_vector_type(4)));
typedef short s16x8 __attribute__((ext_vector_type(8)));
typedef short s16x4 __attribute__((ext_vector_type(4)));
typedef unsigned short u16;

static __device__ __forceinline__ u16 f2bf(float f) {
    union { float f; unsigned int u; } c; c.f = f;
    unsigned int u = c.u;
    unsigned int r = (u + 0x7fffu + ((u >> 16) & 1u)) >> 16;   // RNE
    return (u16)r;
}

// ---------------------------------------------------------------------------
// Kernel 0: transpose+convert weights.  wt[z][n][k] = bf16(W_z[k][n])
// ---------------------------------------------------------------------------
__global__ __launch_bounds__(256) void convw_kernel(
    const float* __restrict__ Wq, const float* __restrict__ Wk,
    const float* __restrict__ Wv, u16* __restrict__ wt)
{
    int i = blockIdx.x * 256 + threadIdx.x;      // < 393216
    int z = i >> 17, r = i & 131071;
    int n = r >> 10, k = r & 1023;
    const float* W = (z == 0) ? Wq : (z == 1) ? Wk : Wv;
    wt[i] = f2bf(W[k * Hh + n]);
}

// ---------------------------------------------------------------------------
// Kernel 1: QKV GEMM, bf16 MFMA 16x16x32.  BM=64, BN=128(full H), BK=64.
// grid = (256,1,3) -> 3 blocks/CU.  4 waves, wave tile 32x64.
// ---------------------------------------------------------------------------
__global__ __launch_bounds__(256, 4) void qkv_gemm(
    const float* __restrict__ x, const u16* __restrict__ wt,
    u16* __restrict__ qo, u16* __restrict__ ko, u16* __restrict__ vo)
{
    __shared__ __align__(16) u16 as[64 * 64];    // 8 KB
    __shared__ __align__(16) u16 bs[128 * 64];   // 16 KB

    const int tid  = threadIdx.x;
    const int m0   = blockIdx.x * 64;
    const int lane = tid & 63, wid = tid >> 6;
    const int wr   = wid >> 1, wc = wid & 1;
    const int l15  = lane & 15, l4 = lane >> 4;

    const u16* W = wt + (size_t)blockIdx.z * 128 * 1024;
    u16* outp = (blockIdx.z == 0) ? qo : (blockIdx.z == 1) ? ko : vo;

    f32x4 acc[2][4];
#pragma unroll
    for (int mi = 0; mi < 2; ++mi)
#pragma unroll
        for (int ni = 0; ni < 4; ++ni) {
            f32x4 z4 = {0.f, 0.f, 0.f, 0.f};
            acc[mi][ni] = z4;
        }

    for (int k0 = 0; k0 < Cc; k0 += 64) {
        // stage A: 64x64 fp32 -> bf16 swizzled (chunk ^= (row&7))
#pragma unroll
        for (int u = 0; u < 4; ++u) {
            int idx = tid + u * 256;             // 0..1023 float4s
            int m = idx >> 4, kf = (idx & 15) * 4;
            float4 xv = *reinterpret_cast<const float4*>(
                &x[(size_t)(m0 + m) * Cc + k0 + kf]);
            s16x4 bv;
            bv[0] = (short)f2bf(xv.x); bv[1] = (short)f2bf(xv.y);
            bv[2] = (short)f2bf(xv.z); bv[3] = (short)f2bf(xv.w);
            *reinterpret_cast<s16x4*>(&as[m * 64 + (kf ^ ((m & 7) << 3))]) = bv;
        }
        // stage B: 128x64 bf16 rows from wt ([n][k]), swizzled
#pragma unroll
        for (int u = 0; u < 4; ++u) {
            int idx = tid + u * 256;             // 0..1023 s16x8s
            int n = idx >> 3, kc = (idx & 7) * 8;
            s16x8 wv = *reinterpret_cast<const s16x8*>(&W[(size_t)n * 1024 + k0 + kc]);
            *reinterpret_cast<s16x8*>(&bs[n * 64 + (kc ^ ((n & 7) << 3))]) = wv;
        }
        __syncthreads();

        s16x8 af[2][2], bfr[4][2];
#pragma unroll
        for (int mi = 0; mi < 2; ++mi) {
            int r = wr * 32 + mi * 16 + l15;
#pragma unroll
            for (int ks = 0; ks < 2; ++ks)
                af[mi][ks] = *reinterpret_cast<const s16x8*>(
                    &as[r * 64 + ((ks * 32 + l4 * 8) ^ ((r & 7) << 3))]);
        }
#pragma unroll
        for (int ni = 0; ni < 4; ++ni) {
            int n = wc * 64 + ni * 16 + l15;
#pragma unroll
            for (int ks = 0; ks < 2; ++ks)
                bfr[ni][ks] = *reinterpret_cast<const s16x8*>(
                    &bs[n * 64 + ((ks * 32 + l4 * 8) ^ ((n & 7) << 3))]);
        }
#pragma unroll
        for (int mi = 0; mi < 2; ++mi)
#pragma unroll
            for (int ni = 0; ni < 4; ++ni)
#pragma unroll
                for (int ks = 0; ks < 2; ++ks)
                    acc[mi][ni] = __builtin_amdgcn_mfma_f32_16x16x32_bf16(
                        af[mi][ks], bfr[ni][ks], acc[mi][ni], 0, 0, 0);
        __syncthreads();
    }

#pragma unroll
    for (int mi = 0; mi < 2; ++mi)
#pragma unroll
        for (int ni = 0; ni < 4; ++ni)
#pragma unroll
            for (int r = 0; r < 4; ++r) {
                int row = m0 + wr * 32 + mi * 16 + l4 * 4 + r;
                int col = wc * 64 + ni * 16 + l15;
                outp[(size_t)row * Hh + col] = f2bf(acc[mi][ni][r]);
            }
}

// ---------------------------------------------------------------------------
// Kernel 2: transpose V.  vt[b][h][t] = v[b][t][h]  (bf16)
// ---------------------------------------------------------------------------
__global__ __launch_bounds__(256) void vtrans_kernel(
    const u16* __restrict__ v, u16* __restrict__ vt)
{
    const int b = blockIdx.y;
    const int t0 = blockIdx.x * 64;
    const int h = threadIdx.x & 127;
    const int part = threadIdx.x >> 7;
    const u16* vb = v + (size_t)b * Tt * Hh;
    u16* vtb = vt + (size_t)b * Hh * Tt;
#pragma unroll
    for (int u = 0; u < 4; ++u) {
        int tt = t0 + (part * 4 + u) * 8;
        union { u16 u[8]; s16x8 v; } tmp;
#pragma unroll
        for (int j = 0; j < 8; ++j) tmp.u[j] = vb[(size_t)(tt + j) * Hh + h];
        *reinterpret_cast<s16x8*>(&vtb[(size_t)h * Tt + tt]) = tmp.v;
    }
}

// ---------------------------------------------------------------------------
// Kernel 3: causal flash attention with in-block KV split.
// Block = 4 waves, SAME 16 q-rows, wave w takes kv-tiles j = w, w+4, ...
// (tile = 64 kv).  K and V^T fragments read DIRECT from global (L2-resident,
// batch pinned to XCD via bid&7).  Zero barriers in main loop; one merge at
// the end via LDS.  grid = 1024 blocks.
// ---------------------------------------------------------------------------
__global__ __launch_bounds__(256, 4) void attn_kernel(
    const u16* __restrict__ q, const u16* __restrict__ k,
    const u16* __restrict__ vt, float* __restrict__ O)
{
    __shared__ float Om[4][16][132];   // partial O per wave (padded)
    __shared__ float ml2[4][2][16];    // m, l per wave per row

    const int tid = threadIdx.x, lane = tid & 63, wid = tid >> 6;
    const int l15 = lane & 15, l4 = lane >> 4;
    const int bid = blockIdx.x;
    const int b = bid & 7;              // batch -> XCD pinning
    const int p = 127 - (bid >> 3);     // heavy q-tiles first
    const int q0 = p * 16;
    const int ntiles = (p + 4) >> 2;    // ceil(16(p+1)/64)

    const u16* qb = q  + (size_t)b * Tt * Hh;
    const u16* kb = k  + (size_t)b * Tt * Hh;
    const u16* vb = vt + (size_t)b * Hh * Tt;

    // per-wave P scratch aliases the (later-written) Om[wid] region
    u16* ps = reinterpret_cast<u16*>(&Om[wid][0][0]);   // 2 KB used of 8.4 KB

    // Q fragments (A-operand), same 16 rows for all 4 waves
    s16x8 qf[4];
#pragma unroll
    for (int ks = 0; ks < 4; ++ks)
        qf[ks] = *reinterpret_cast<const s16x8*>(
            &qb[(size_t)(q0 + l15) * Hh + ks * 32 + l4 * 8]);

    f32x4 o[8];
#pragma unroll
    for (int nh = 0; nh < 8; ++nh) { f32x4 z4 = {0.f,0.f,0.f,0.f}; o[nh] = z4; }
    float mreg[4], lreg[4];
#pragma unroll
    for (int r = 0; r < 4; ++r) { mreg[r] = -1e30f; lreg[r] = 0.f; }

    for (int j = wid; j < ntiles; j += 4) {
        const int kv0 = j * 64;
        const bool diag = (j == ntiles - 1);

        // S = Q K^T : 16 MFMAs, K frags direct from global (L2)
        f32x4 sacc[4];
#pragma unroll
        for (int nf = 0; nf < 4; ++nf) { f32x4 z4 = {0.f,0.f,0.f,0.f}; sacc[nf] = z4; }
#pragma unroll
        for (int nf = 0; nf < 4; ++nf)
#pragma unroll
            for (int ks = 0; ks < 4; ++ks) {
                s16x8 kf = *reinterpret_cast<const s16x8*>(
                    &kb[(size_t)(kv0 + nf * 16 + l15) * Hh + ks * 32 + l4 * 8]);
                sacc[nf] = __builtin_amdgcn_mfma_f32_16x16x32_bf16(
                    qf[ks], kf, sacc[nf], 0, 0, 0);
            }

        // scale + causal mask + online softmax (private state, no barriers)
        float pv2[4][4];
#pragma unroll
        for (int nf = 0; nf < 4; ++nf)
#pragma unroll
            for (int r = 0; r < 4; ++r) {
                float s = sacc[nf][r] * kScale;
                if (diag) {
                    int qq = q0 + l4 * 4 + r;
                    int kk = kv0 + nf * 16 + l15;
                    if (kk > qq) s = -1e30f;
                }
                pv2[nf][r] = s;
            }
#pragma unroll
        for (int r = 0; r < 4; ++r) {
            float mx = fmaxf(fmaxf(pv2[0][r], pv2[1][r]), fmaxf(pv2[2][r], pv2[3][r]));
            mx = fmaxf(mx, __shfl_xor(mx, 1));
            mx = fmaxf(mx, __shfl_xor(mx, 2));
            mx = fmaxf(mx, __shfl_xor(mx, 4));
            mx = fmaxf(mx, __shfl_xor(mx, 8));
            float mnew = fmaxf(mreg[r], mx);
            float scl = __expf(mreg[r] - mnew);
            mreg[r] = mnew;
            float rs = 0.f;
#pragma unroll
            for (int nf = 0; nf < 4; ++nf) {
                float pp = __expf(pv2[nf][r] - mnew);
                pv2[nf][r] = pp; rs += pp;
            }
            rs += __shfl_xor(rs, 1); rs += __shfl_xor(rs, 2);
            rs += __shfl_xor(rs, 4); rs += __shfl_xor(rs, 8);
            lreg[r] = lreg[r] * scl + rs;
#pragma unroll
            for (int nh = 0; nh < 8; ++nh) o[nh][r] *= scl;
        }

        // P -> per-wave LDS (bf16, swizzled) for A-fragment transpose
#pragma unroll
        for (int nf = 0; nf < 4; ++nf)
#pragma unroll
            for (int r = 0; r < 4; ++r) {
                int row = l4 * 4 + r, col = nf * 16 + l15;
                ps[row * 64 + (col ^ ((row & 7) << 3))] = f2bf(pv2[nf][r]);
            }

        // O += P V : 16 MFMAs, V^T frags direct from global (L2)
#pragma unroll
        for (int ks2 = 0; ks2 < 2; ++ks2) {
            s16x8 pa = *reinterpret_cast<const s16x8*>(
                &ps[l15 * 64 + ((ks2 * 32 + l4 * 8) ^ ((l15 & 7) << 3))]);
#pragma unroll
            for (int nh = 0; nh < 8; ++nh) {
                s16x8 vf = *reinterpret_cast<const s16x8*>(
                    &vb[(size_t)(nh * 16 + l15) * Tt + kv0 + ks2 * 32 + l4 * 8]);
                o[nh] = __builtin_amdgcn_mfma_f32_16x16x32_bf16(pa, vf, o[nh], 0, 0, 0);
            }
        }
    }

    // publish partials
#pragma unroll
    for (int nh = 0; nh < 8; ++nh)
#pragma unroll
        for (int r = 0; r < 4; ++r)
            Om[wid][l4 * 4 + r][nh * 16 + l15] = o[nh][r];
    if (l15 == 0) {
#pragma unroll
        for (int r = 0; r < 4; ++r) {
            ml2[wid][0][l4 * 4 + r] = mreg[r];
            ml2[wid][1][l4 * 4 + r] = lreg[r];
        }
    }
    __syncthreads();

    // merge 4 partials: thread owns (row, 8-col chunk)
    {
        const int row = tid >> 4, ch = tid & 15;
        float M = -1e30f;
#pragma unroll
        for (int w = 0; w < 4; ++w) M = fmaxf(M, ml2[w][0][row]);
        float L = 0.f;
        float a[8];
#pragma unroll
        for (int c = 0; c < 8; ++c) a[c] = 0.f;
#pragma unroll
        for (int w = 0; w < 4; ++w) {
            float f = __expf(ml2[w][0][row] - M);
            L += f * ml2[w][1][row];
#pragma unroll
            for (int c = 0; c < 8; ++c) a[c] += f * Om[w][row][ch * 8 + c];
        }
        float inv = 1.f / L;
        float4 o0 = make_float4(a[0]*inv, a[1]*inv, a[2]*inv, a[3]*inv);
        float4 o1 = make_float4(a[4]*inv, a[5]*inv, a[6]*inv, a[7]*inv);
        float* orow = O + ((size_t)(b * Tt) + q0 + row) * Hh + ch * 8;
        *reinterpret_cast<float4*>(orow) = o0;
        *reinterpret_cast<float4*>(orow + 4) = o1;
    }
}

// ---------------------------------------------------------------------------
// Kernel 4: in-place output projection (fp32).  BM=32, grid 512.
// ---------------------------------------------------------------------------
__global__ __launch_bounds__(256) void proj_kernel(
    float* __restrict__ io, const float* __restrict__ Wp,
    const float* __restrict__ bp)
{
    __shared__ float os[32][128];
    const int tid = threadIdx.x;
    const int m0  = blockIdx.x * 32;
#pragma unroll
    for (int u = 0; u < 4; ++u) {
        int idx = tid + u * 256;             // 1024 float4s
        int r = idx >> 5, c = (idx & 31) * 4;
        *reinterpret_cast<float4*>(&os[r][c]) =
            *reinterpret_cast<const float4*>(&io[(size_t)(m0 + r) * Hh + c]);
    }
    __syncthreads();

    const int h  = tid & 127;
    const int rr = tid >> 7;
    float acc[16];
#pragma unroll
    for (int i = 0; i < 16; ++i) acc[i] = 0.f;
    for (int kk = 0; kk < 128; ++kk) {
        float w = Wp[kk * Hh + h];
#pragma unroll
        for (int i = 0; i < 16; ++i) acc[i] += os[rr * 16 + i][kk] * w;
    }
    float bv = bp[h];
#pragma unroll
    for (int i = 0; i < 16; ++i)
        io[(size_t)(m0 + rr * 16 + i) * Hh + h] = acc[i] + bv;
}

// ---------------------------------------------------------------------------
extern "C" void kernel_launch(void* const* d_in, const int* in_sizes, int n_in,
                              void* d_out, int out_size, void* d_ws, size_t ws_size,
                              hipStream_t stream) {
    const float* x  = (const float*)d_in[0];
    const float* Wk = (const float*)d_in[1];
    const float* Wq = (const float*)d_in[2];
    const float* Wv = (const float*)d_in[3];
    const float* Wp = (const float*)d_in[4];
    const float* bp = (const float*)d_in[5];
    float* out = (float*)d_out;

    // workspace layout (ushorts): wt 393216 | qw 2M | kw 2M | vw 2M | vt 2M
    u16* wtb = (u16*)d_ws;
    u16* qw = wtb + 393216;
    u16* kw = qw + (size_t)Mrows * Hh;
    u16* vw = kw + (size_t)Mrows * Hh;
    u16* vtb = vw + (size_t)Mrows * Hh;   // total ~17.6 MB

    convw_kernel<<<1536, 256, 0, stream>>>(Wq, Wk, Wv, wtb);
    qkv_gemm<<<dim3(Mrows / 64, 1, 3), 256, 0, stream>>>(x, wtb, qw, kw, vw);
    vtrans_kernel<<<dim3(Tt / 64, Bz), 256, 0, stream>>>(vw, vtb);
    attn_kernel<<<1024, 256, 0, stream>>>(qw, kw, vtb, out);
    proj_kernel<<<dim3(Mrows / 32), 256, 0, stream>>>(out, Wp, bp);
}

// Round 4
// 138.566 us; speedup vs baseline: 4.7173x; 1.1437x over previous
//
#include <hip/hip_runtime.h>

// Problem constants (B,T,C,H) = (8, 2048, 1024, 128)
constexpr int Bz = 8, Tt = 2048, Cc = 1024, Hh = 128;
constexpr int Mrows = Bz * Tt;                 // 16384
constexpr float kScale = 0.08838834764831843f; // 1/sqrt(128)

typedef float f32x4 __attribute__((ext_vector_type(4)));
typedef short s16x8 __attribute__((ext_vector_type(8)));
typedef short s16x4 __attribute__((ext_vector_type(4)));
typedef unsigned short u16;

static __device__ __forceinline__ u16 f2bf(float f) {
    union { float f; unsigned int u; } c; c.f = f;
    unsigned int u = c.u;
    unsigned int r = (u + 0x7fffu + ((u >> 16) & 1u)) >> 16;   // RNE
    return (u16)r;
}

// ---------------------------------------------------------------------------
// Kernel 0: transpose+convert weights.
//   i < 393216 : wt[z][n][k] = bf16(W_z[k][n])   (z: 0=Wq,1=Wk,2=Wv)
//   else       : wpt[n][k]   = bf16(Wp[k][n])    (16384 elems)
// ---------------------------------------------------------------------------
__global__ __launch_bounds__(256) void convw_kernel(
    const float* __restrict__ Wq, const float* __restrict__ Wk,
    const float* __restrict__ Wv, const float* __restrict__ Wp,
    u16* __restrict__ wt, u16* __restrict__ wpt)
{
    int i = blockIdx.x * 256 + threadIdx.x;      // < 409600
    if (i < 393216) {
        int z = i >> 17, r = i & 131071;
        int n = r >> 10, k = r & 1023;
        const float* W = (z == 0) ? Wq : (z == 1) ? Wk : Wv;
        wt[i] = f2bf(W[k * Hh + n]);
    } else {
        int r2 = i - 393216;                     // n*128 + k
        int n = r2 >> 7, k = r2 & 127;
        wpt[r2] = f2bf(Wp[k * Hh + n]);
    }
}

// ---------------------------------------------------------------------------
// Kernel 1: QKV GEMM, bf16 MFMA 16x16x32.  BM=64, BN=128(full H), BK=64.
// (unchanged from round 3)
// ---------------------------------------------------------------------------
__global__ __launch_bounds__(256, 4) void qkv_gemm(
    const float* __restrict__ x, const u16* __restrict__ wt,
    u16* __restrict__ qo, u16* __restrict__ ko, u16* __restrict__ vo)
{
    __shared__ __align__(16) u16 as[64 * 64];    // 8 KB
    __shared__ __align__(16) u16 bs[128 * 64];   // 16 KB

    const int tid  = threadIdx.x;
    const int m0   = blockIdx.x * 64;
    const int lane = tid & 63, wid = tid >> 6;
    const int wr   = wid >> 1, wc = wid & 1;
    const int l15  = lane & 15, l4 = lane >> 4;

    const u16* W = wt + (size_t)blockIdx.z * 128 * 1024;
    u16* outp = (blockIdx.z == 0) ? qo : (blockIdx.z == 1) ? ko : vo;

    f32x4 acc[2][4];
#pragma unroll
    for (int mi = 0; mi < 2; ++mi)
#pragma unroll
        for (int ni = 0; ni < 4; ++ni) {
            f32x4 z4 = {0.f, 0.f, 0.f, 0.f};
            acc[mi][ni] = z4;
        }

    for (int k0 = 0; k0 < Cc; k0 += 64) {
#pragma unroll
        for (int u = 0; u < 4; ++u) {
            int idx = tid + u * 256;
            int m = idx >> 4, kf = (idx & 15) * 4;
            float4 xv = *reinterpret_cast<const float4*>(
                &x[(size_t)(m0 + m) * Cc + k0 + kf]);
            s16x4 bv;
            bv[0] = (short)f2bf(xv.x); bv[1] = (short)f2bf(xv.y);
            bv[2] = (short)f2bf(xv.z); bv[3] = (short)f2bf(xv.w);
            *reinterpret_cast<s16x4*>(&as[m * 64 + (kf ^ ((m & 7) << 3))]) = bv;
        }
#pragma unroll
        for (int u = 0; u < 4; ++u) {
            int idx = tid + u * 256;
            int n = idx >> 3, kc = (idx & 7) * 8;
            s16x8 wv = *reinterpret_cast<const s16x8*>(&W[(size_t)n * 1024 + k0 + kc]);
            *reinterpret_cast<s16x8*>(&bs[n * 64 + (kc ^ ((n & 7) << 3))]) = wv;
        }
        __syncthreads();

        s16x8 af[2][2], bfr[4][2];
#pragma unroll
        for (int mi = 0; mi < 2; ++mi) {
            int r = wr * 32 + mi * 16 + l15;
#pragma unroll
            for (int ks = 0; ks < 2; ++ks)
                af[mi][ks] = *reinterpret_cast<const s16x8*>(
                    &as[r * 64 + ((ks * 32 + l4 * 8) ^ ((r & 7) << 3))]);
        }
#pragma unroll
        for (int ni = 0; ni < 4; ++ni) {
            int n = wc * 64 + ni * 16 + l15;
#pragma unroll
            for (int ks = 0; ks < 2; ++ks)
                bfr[ni][ks] = *reinterpret_cast<const s16x8*>(
                    &bs[n * 64 + ((ks * 32 + l4 * 8) ^ ((n & 7) << 3))]);
        }
#pragma unroll
        for (int mi = 0; mi < 2; ++mi)
#pragma unroll
            for (int ni = 0; ni < 4; ++ni)
#pragma unroll
                for (int ks = 0; ks < 2; ++ks)
                    acc[mi][ni] = __builtin_amdgcn_mfma_f32_16x16x32_bf16(
                        af[mi][ks], bfr[ni][ks], acc[mi][ni], 0, 0, 0);
        __syncthreads();
    }

#pragma unroll
    for (int mi = 0; mi < 2; ++mi)
#pragma unroll
        for (int ni = 0; ni < 4; ++ni)
#pragma unroll
            for (int r = 0; r < 4; ++r) {
                int row = m0 + wr * 32 + mi * 16 + l4 * 4 + r;
                int col = wc * 64 + ni * 16 + l15;
                outp[(size_t)row * Hh + col] = f2bf(acc[mi][ni][r]);
            }
}

// ---------------------------------------------------------------------------
// Kernel 2: transpose V.  vt[b][h][t] = v[b][t][h]  (bf16)
// ---------------------------------------------------------------------------
__global__ __launch_bounds__(256) void vtrans_kernel(
    const u16* __restrict__ v, u16* __restrict__ vt)
{
    const int b = blockIdx.y;
    const int t0 = blockIdx.x * 64;
    const int h = threadIdx.x & 127;
    const int part = threadIdx.x >> 7;
    const u16* vb = v + (size_t)b * Tt * Hh;
    u16* vtb = vt + (size_t)b * Hh * Tt;
#pragma unroll
    for (int u = 0; u < 4; ++u) {
        int tt = t0 + (part * 4 + u) * 8;
        union { u16 u[8]; s16x8 v; } tmp;
#pragma unroll
        for (int j = 0; j < 8; ++j) tmp.u[j] = vb[(size_t)(tt + j) * Hh + h];
        *reinterpret_cast<s16x8*>(&vtb[(size_t)h * Tt + tt]) = tmp.v;
    }
}

// ---------------------------------------------------------------------------
// Kernel 3: causal flash attention, in-block KV split, software-pipelined,
// fused output projection.
//   Block = 4 waves, same 16 q-rows; wave w: kv-tiles (32 wide) j = w, w+4, ...
//   K double-buffered in regs (next tile issued right after QK^T);
//   V issued at iter top, consumed after softmax.  Zero main-loop barriers.
//   Epilogue: LDS merge of 4 partials -> bf16 -> MFMA projection vs Wp^T + bias.
// ---------------------------------------------------------------------------
__global__ __launch_bounds__(256, 3) void attn_kernel(
    const u16* __restrict__ q, const u16* __restrict__ k,
    const u16* __restrict__ vt, const u16* __restrict__ wpt,
    const float* __restrict__ bp, float* __restrict__ O)
{
    __shared__ float Om[4][16][132];     // 33792 B (partial O per wave)
    __shared__ float ml2[4][2][16];      // 512 B
    __shared__ __align__(16) u16 pm[16 * 136];  // 4352 B merged bf16 O

    const int tid = threadIdx.x, lane = tid & 63, wid = tid >> 6;
    const int l15 = lane & 15, l4 = lane >> 4;
    const int bid = blockIdx.x;
    const int b = bid & 7;               // batch -> XCD pinning
    const int p = 127 - (bid >> 3);      // heavy q-tiles first
    const int q0 = p * 16;
    const int ntiles = (p + 2) >> 1;     // ceil(16(p+1)/32)

    const u16* qb = q  + (size_t)b * Tt * Hh;
    const u16* kb = k  + (size_t)b * Tt * Hh;
    const u16* vb = vt + (size_t)b * Hh * Tt;

    // per-wave P scratch aliases Om[wid] (16 x 40 u16 = 1280 B, stride 40 pads banks)
    u16* ps = reinterpret_cast<u16*>(&Om[wid][0][0]);

    // Q fragments (A-operand), same 16 rows for all 4 waves
    s16x8 qf[4];
#pragma unroll
    for (int ks = 0; ks < 4; ++ks)
        qf[ks] = *reinterpret_cast<const s16x8*>(
            &qb[(size_t)(q0 + l15) * Hh + ks * 32 + l4 * 8]);

    f32x4 o[8];
#pragma unroll
    for (int nh = 0; nh < 8; ++nh) { f32x4 z4 = {0.f,0.f,0.f,0.f}; o[nh] = z4; }
    float mreg[4], lreg[4];
#pragma unroll
    for (int r = 0; r < 4; ++r) { mreg[r] = -1e30f; lreg[r] = 0.f; }

    int j = wid;
    s16x8 kf[8];                         // current K tile frags (2 nf x 4 ks)
    if (j < ntiles) {
        const int kv0 = j * 32;
#pragma unroll
        for (int nf = 0; nf < 2; ++nf)
#pragma unroll
            for (int ks = 0; ks < 4; ++ks)
                kf[nf * 4 + ks] = *reinterpret_cast<const s16x8*>(
                    &kb[(size_t)(kv0 + nf * 16 + l15) * Hh + ks * 32 + l4 * 8]);
    }

    for (; j < ntiles; j += 4) {
        const int kv0 = j * 32;
        const bool diag = (j == ntiles - 1);

        // issue V loads for this tile (consumed after softmax)
        s16x8 vf[8];
#pragma unroll
        for (int nh = 0; nh < 8; ++nh)
            vf[nh] = *reinterpret_cast<const s16x8*>(
                &vb[(size_t)(nh * 16 + l15) * Tt + kv0 + l4 * 8]);

        // S = Q K^T : 8 MFMAs from resident kf
        f32x4 sacc[2];
#pragma unroll
        for (int nf = 0; nf < 2; ++nf) { f32x4 z4 = {0.f,0.f,0.f,0.f}; sacc[nf] = z4; }
#pragma unroll
        for (int nf = 0; nf < 2; ++nf)
#pragma unroll
            for (int ks = 0; ks < 4; ++ks)
                sacc[nf] = __builtin_amdgcn_mfma_f32_16x16x32_bf16(
                    qf[ks], kf[nf * 4 + ks], sacc[nf], 0, 0, 0);

        // prefetch next K tile into kf (kf dead after QK^T)
        {
            const int jn = (j + 4 < ntiles) ? (j + 4) : j;   // clamp: valid addr
            const int kvn = jn * 32;
#pragma unroll
            for (int nf = 0; nf < 2; ++nf)
#pragma unroll
                for (int ks = 0; ks < 4; ++ks)
                    kf[nf * 4 + ks] = *reinterpret_cast<const s16x8*>(
                        &kb[(size_t)(kvn + nf * 16 + l15) * Hh + ks * 32 + l4 * 8]);
        }

        // scale + causal mask + online softmax (private state)
        float pv2[2][4];
#pragma unroll
        for (int nf = 0; nf < 2; ++nf)
#pragma unroll
            for (int r = 0; r < 4; ++r) {
                float s = sacc[nf][r] * kScale;
                if (diag) {
                    int qq = q0 + l4 * 4 + r;
                    int kk = kv0 + nf * 16 + l15;
                    if (kk > qq) s = -1e30f;
                }
                pv2[nf][r] = s;
            }
#pragma unroll
        for (int r = 0; r < 4; ++r) {
            float mx = fmaxf(pv2[0][r], pv2[1][r]);
            mx = fmaxf(mx, __shfl_xor(mx, 1));
            mx = fmaxf(mx, __shfl_xor(mx, 2));
            mx = fmaxf(mx, __shfl_xor(mx, 4));
            mx = fmaxf(mx, __shfl_xor(mx, 8));
            float mnew = fmaxf(mreg[r], mx);
            float scl = __expf(mreg[r] - mnew);
            mreg[r] = mnew;
            float rs = 0.f;
#pragma unroll
            for (int nf = 0; nf < 2; ++nf) {
                float pp = __expf(pv2[nf][r] - mnew);
                pv2[nf][r] = pp; rs += pp;
            }
            rs += __shfl_xor(rs, 1); rs += __shfl_xor(rs, 2);
            rs += __shfl_xor(rs, 4); rs += __shfl_xor(rs, 8);
            lreg[r] = lreg[r] * scl + rs;
#pragma unroll
            for (int nh = 0; nh < 8; ++nh) o[nh][r] *= scl;
        }

        // P -> per-wave LDS (bf16, stride-40 padded)
#pragma unroll
        for (int nf = 0; nf < 2; ++nf)
#pragma unroll
            for (int r = 0; r < 4; ++r)
                ps[(l4 * 4 + r) * 40 + nf * 16 + l15] = f2bf(pv2[nf][r]);

        // O += P V : 8 MFMAs (vf issued ~600cy ago)
        s16x8 pa = *reinterpret_cast<const s16x8*>(&ps[l15 * 40 + l4 * 8]);
#pragma unroll
        for (int nh = 0; nh < 8; ++nh)
            o[nh] = __builtin_amdgcn_mfma_f32_16x16x32_bf16(pa, vf[nh], o[nh], 0, 0, 0);
    }

    // publish partials
#pragma unroll
    for (int nh = 0; nh < 8; ++nh)
#pragma unroll
        for (int r = 0; r < 4; ++r)
            Om[wid][l4 * 4 + r][nh * 16 + l15] = o[nh][r];
    if (l15 == 0) {
#pragma unroll
        for (int r = 0; r < 4; ++r) {
            ml2[wid][0][l4 * 4 + r] = mreg[r];
            ml2[wid][1][l4 * 4 + r] = lreg[r];
        }
    }
    __syncthreads();

    // merge 4 partials -> normalized bf16 row block pm[16][128] (stride 136)
    {
        const int row = tid >> 4, ch = tid & 15;
        float M = -1e30f;
#pragma unroll
        for (int w = 0; w < 4; ++w) M = fmaxf(M, ml2[w][0][row]);
        float L = 0.f;
        float a[8];
#pragma unroll
        for (int c = 0; c < 8; ++c) a[c] = 0.f;
#pragma unroll
        for (int w = 0; w < 4; ++w) {
            float f = __expf(ml2[w][0][row] - M);
            L += f * ml2[w][1][row];
#pragma unroll
            for (int c = 0; c < 8; ++c) a[c] += f * Om[w][row][ch * 8 + c];
        }
        float inv = 1.f / L;
        union { u16 u[8]; s16x8 v; } pk;
#pragma unroll
        for (int c = 0; c < 8; ++c) pk.u[c] = f2bf(a[c] * inv);
        *reinterpret_cast<s16x8*>(&pm[row * 136 + ch * 8]) = pk.v;
    }
    __syncthreads();

    // fused projection: out[q][n] = pm[q][:] @ WpT[n][:] + bp[n]
    {
        s16x8 af2[4];
#pragma unroll
        for (int ks = 0; ks < 4; ++ks)
            af2[ks] = *reinterpret_cast<const s16x8*>(
                &pm[l15 * 136 + ks * 32 + l4 * 8]);
#pragma unroll
        for (int ni2 = 0; ni2 < 2; ++ni2) {
            const int ncol = (wid * 2 + ni2) * 16 + l15;
            f32x4 pacc = {0.f, 0.f, 0.f, 0.f};
#pragma unroll
            for (int ks = 0; ks < 4; ++ks) {
                s16x8 wf = *reinterpret_cast<const s16x8*>(
                    &wpt[(size_t)ncol * 128 + ks * 32 + l4 * 8]);
                pacc = __builtin_amdgcn_mfma_f32_16x16x32_bf16(af2[ks], wf, pacc, 0, 0, 0);
            }
            float bias = bp[ncol];
#pragma unroll
            for (int r = 0; r < 4; ++r)
                O[((size_t)(b * Tt) + q0 + l4 * 4 + r) * Hh + ncol] = pacc[r] + bias;
        }
    }
}

// ---------------------------------------------------------------------------
extern "C" void kernel_launch(void* const* d_in, const int* in_sizes, int n_in,
                              void* d_out, int out_size, void* d_ws, size_t ws_size,
                              hipStream_t stream) {
    const float* x  = (const float*)d_in[0];
    const float* Wk = (const float*)d_in[1];
    const float* Wq = (const float*)d_in[2];
    const float* Wv = (const float*)d_in[3];
    const float* Wp = (const float*)d_in[4];
    const float* bp = (const float*)d_in[5];
    float* out = (float*)d_out;

    // workspace (u16): wt 393216 | wpt 16384 | qw 2M | kw 2M | vw 2M | vt 2M
    u16* wtb = (u16*)d_ws;
    u16* wpt = wtb + 393216;
    u16* qw  = wpt + 16384;
    u16* kw  = qw + (size_t)Mrows * Hh;
    u16* vw  = kw + (size_t)Mrows * Hh;
    u16* vtb = vw + (size_t)Mrows * Hh;   // total ~17.6 MB

    convw_kernel<<<1600, 256, 0, stream>>>(Wq, Wk, Wv, Wp, wtb, wpt);
    qkv_gemm<<<dim3(Mrows / 64, 1, 3), 256, 0, stream>>>(x, wtb, qw, kw, vw);
    vtrans_kernel<<<dim3(Tt / 64, Bz), 256, 0, stream>>>(vw, vtb);
    attn_kernel<<<1024, 256, 0, stream>>>(qw, kw, vtb, wpt, bp, out);
}